// Round 1
// 1644.609 us; speedup vs baseline: 1.1165x; 1.1165x over previous
//
#include <hip/hip_runtime.h>
#include <cstdint>
#include <cstddef>

#define NB 64          // batch (queries)
#define DD 256         // feature dim
#define NKEYS 500000
#define TOPK 32
#define NW 4096        // number of streaming waves (1 wave = 1 block of 64)
#define NTILES ((NKEYS + 63) / 64)   // 7813
#define CPW 4          // candidates kept per (wave, query) -- in registers

// ---- float <-> order-preserving u32 ----
__device__ __forceinline__ unsigned int f2sort(float f) {
  unsigned int u = __float_as_uint(f);
  return u ^ ((unsigned int)((int)u >> 31) | 0x80000000u);
}
__device__ __forceinline__ float sort2f(unsigned int u) {
  unsigned int b = (u & 0x80000000u) ? (u ^ 0x80000000u) : ~u;
  return __uint_as_float(b);
}

// ---- K1: q_proj = (query @ Wq^T + bq) * (1/16 * log2(e)) -> qs [64][256] ----
// scores are kept in base-2 domain from here on: exp(s/16) == exp2(s * 0.0625*log2e)
__global__ __launch_bounds__(256) void qproj_kernel(
    const float* __restrict__ query, const float* __restrict__ Wq,
    const float* __restrict__ bq, float* __restrict__ qs) {
  const int b = blockIdx.x;      // query row
  const int j = threadIdx.x;     // output feature
  const float4* wr = (const float4*)(Wq + (size_t)j * DD);
  float acc = bq[j];
  for (int dq = 0; dq < DD / 4; ++dq) {
    float4 wv = wr[dq];
    float4 qv = *(const float4*)(query + b * DD + dq * 4);  // wave-uniform -> s_load
    acc = fmaf(qv.x, wv.x, acc);
    acc = fmaf(qv.y, wv.y, acc);
    acc = fmaf(qv.z, wv.z, acc);
    acc = fmaf(qv.w, wv.w, acc);
  }
  qs[b * DD + j] = acc * (0.0625f * 1.4426950408889634f);
}

// ---- K2: stream keys, scores for all 64 queries, raw exp2-sum + reg top-CPW ----
__global__ __launch_bounds__(64) void score_topk_kernel(
    const float* __restrict__ keys, const float* __restrict__ qs,
    float* __restrict__ sums, unsigned long long* __restrict__ cands) {
  __shared__ float sc[NB * 17];       // 4352 B: [query][key-in-phase], stride 17 = conflict-free
  const int lane = threadIdx.x;       // = key-in-tile for compute, = query for bookkeeping
  const int w = blockIdx.x;

  float sum = 0.f;                    // sum of exp2(s), no max subtraction (fp32 range ok)
  float thr = -3.402823466e+38f;      // float gate = score of current min candidate
  // candidate regs, packed (f2sort(score)<<32)|~key. Sentinels: f2sort(-FLT_MAX)=0x00800000,
  // distinct low words, below every real (finite) key, above nothing that matters.
  unsigned long long c0 = 0x0080000000000000ull | 0u;
  unsigned long long c1 = 0x0080000000000000ull | 1u;
  unsigned long long c2 = 0x0080000000000000ull | 2u;
  unsigned long long c3 = 0x0080000000000000ull | 3u;

  for (int t = w; t < NTILES; t += NW) {
    const int key0 = t * 64 + lane;
    const bool valid = key0 < NKEYS;
    const float4* kr4 = (const float4*)(keys + (size_t)(valid ? key0 : 0) * DD);

    float acc[NB];
#pragma unroll
    for (int b = 0; b < NB; ++b) acc[b] = 0.f;

    float4 kv = kr4[0];
    for (int dq = 0; dq < DD / 4; ++dq) {
      const int dn = (dq + 1 < DD / 4) ? dq + 1 : dq;
      float4 nkv = kr4[dn];           // prefetch (branchless)
      const int d0 = dq * 4;
#pragma unroll
      for (int b = 0; b < NB; ++b) {
        float4 qv = *(const float4*)(qs + b * DD + d0);  // uniform -> s_load_dwordx4
        acc[b] = fmaf(qv.x, kv.x, acc[b]);
        acc[b] = fmaf(qv.y, kv.y, acc[b]);
        acc[b] = fmaf(qv.z, kv.z, acc[b]);
        acc[b] = fmaf(qv.w, kv.w, acc[b]);
      }
      kv = nkv;
    }
    if (!valid) {
#pragma unroll
      for (int b = 0; b < NB; ++b) acc[b] = -INFINITY;   // exp2(-inf)=0, gate always fails
    }

    // transpose + bookkeeping in 4 phases of 16 keys (LDS = 4.3 KB, not 16.9 KB)
    for (int p = 0; p < 4; ++p) {
      if ((lane >> 4) == p) {
        const int col = lane & 15;
#pragma unroll
        for (int b = 0; b < NB; ++b) sc[b * 17 + col] = acc[b];
      }
      __syncthreads();
      const int kbase = t * 64 + p * 16;
#pragma unroll
      for (int k2 = 0; k2 < 16; ++k2) {
        float s = sc[lane * 17 + k2];
        sum += exp2f(s);
        if (s >= thr) {               // rare after warm-up; pack/insert only then
          unsigned long long pk =
              ((unsigned long long)f2sort(s) << 32) | (unsigned int)(~(kbase + k2));
          unsigned long long m01 = c0 < c1 ? c0 : c1;
          unsigned long long m23 = c2 < c3 ? c2 : c3;
          unsigned long long mn = m01 < m23 ? m01 : m23;
          if (pk > mn) {              // ties broken by index (lower idx wins), matches top_k
            if (c0 == mn) c0 = pk;
            else if (c1 == mn) c1 = pk;
            else if (c2 == mn) c2 = pk;
            else c3 = pk;
            m01 = c0 < c1 ? c0 : c1;
            m23 = c2 < c3 ? c2 : c3;
            mn = m01 < m23 ? m01 : m23;
            thr = sort2f((unsigned int)(mn >> 32));
          }
        }
      }
      __syncthreads();
    }
  }

  sums[(size_t)w * NB + lane] = sum;
  unsigned long long* myc = cands + ((size_t)w * NB + lane) * CPW;
  myc[0] = c0; myc[1] = c1; myc[2] = c2; myc[3] = c3;
}

// ---- K3: per query sum partial denominators + global top-32 ----
__global__ __launch_bounds__(256) void merge_kernel(
    const float* __restrict__ sums, const unsigned long long* __restrict__ cands,
    int* __restrict__ sel_idx, float* __restrict__ sel_w) {
  const int b = blockIdx.x;
  const int tid = threadIdx.x;
  __shared__ float red_s[256];
  __shared__ unsigned long long pool[256 * 8];
  __shared__ unsigned long long red[256];

  // phase A: plain sum of exp2-partials (no rescaling needed)
  float S = 0.f;
  for (int w = tid; w < NW; w += 256) S += sums[(size_t)w * NB + b];
  red_s[tid] = S;

  // phase B: per-thread local top-8 of its candidate slice (NW*CPW/256 = 64 each)
  unsigned long long* mine = pool + tid * 8;
#pragma unroll
  for (int i = 0; i < 8; ++i) mine[i] = 0ull;
  unsigned long long lmin = 0ull; int lpos = 0;
  for (int w = tid; w < NW; w += 256) {
    const unsigned long long* src = cands + ((size_t)w * NB + b) * CPW;
#pragma unroll
    for (int j = 0; j < CPW; ++j) {
      unsigned long long pk = src[j];
      if (pk > lmin) {
        mine[lpos] = pk;
        lmin = mine[0]; lpos = 0;
#pragma unroll
        for (int i = 1; i < 8; ++i)
          if (mine[i] < lmin) { lmin = mine[i]; lpos = i; }
      }
    }
  }
  __syncthreads();

  // reduce S
  for (int off = 128; off > 0; off >>= 1) {
    if (tid < off) red_s[tid] += red_s[tid + off];
    __syncthreads();
  }
  const float Sf = red_s[0];

  // phase C: 32 rounds of block-wide argmax over the 2048-entry pool
  for (int r = 0; r < TOPK; ++r) {
    unsigned long long best = 0ull;
    for (int i = tid; i < 2048; i += 256) {
      unsigned long long v = pool[i];
      if (v > best) best = v;
    }
    red[tid] = best;
    __syncthreads();
    for (int off = 128; off > 0; off >>= 1) {
      if (tid < off) { if (red[tid + off] > red[tid]) red[tid] = red[tid + off]; }
      __syncthreads();
    }
    best = red[0];
    for (int i = tid; i < 2048; i += 256) {
      if (pool[i] == best) pool[i] = 0ull;   // unique (contains ~key_idx)
    }
    if (tid == 0) {
      float s = sort2f((unsigned int)(best >> 32));
      sel_idx[b * TOPK + r] = (int)(~(unsigned int)best);
      sel_w[b * TOPK + r] = exp2f(s) / Sf;
    }
    __syncthreads();
  }
}

// ---- K4: gather values rows + write weights ----
__global__ __launch_bounds__(64) void gather_kernel(
    const float* __restrict__ values, const int* __restrict__ sel_idx,
    const float* __restrict__ sel_w, float* __restrict__ out) {
  const int row = blockIdx.x;          // b*32 + j
  const int tid = threadIdx.x;
  const int idx = sel_idx[row];
  const float4* src = (const float4*)(values + (size_t)idx * DD);
  float4* dst = (float4*)(out + (size_t)row * DD);
  dst[tid] = src[tid];
  if (tid == 0) out[(size_t)NB * TOPK * DD + row] = sel_w[row];
}

extern "C" void kernel_launch(void* const* d_in, const int* in_sizes, int n_in,
                              void* d_out, int out_size, void* d_ws, size_t ws_size,
                              hipStream_t stream) {
  (void)in_sizes; (void)n_in; (void)out_size; (void)ws_size;
  const float* query  = (const float*)d_in[0];
  const float* keys   = (const float*)d_in[1];
  const float* values = (const float*)d_in[2];
  const float* Wq     = (const float*)d_in[3];
  const float* bq     = (const float*)d_in[4];
  float* out = (float*)d_out;

  // workspace carve-up (all 256B aligned); total ~9.1 MB
  char* ws = (char*)d_ws;
  size_t off = 0;
  float* qs = (float*)(ws + off);                    off += (size_t)NB * DD * 4;          // 64 KB
  float* sums = (float*)(ws + off);                  off += (size_t)NW * NB * 4;          // 1 MB
  unsigned long long* cands =
      (unsigned long long*)(ws + off);               off += (size_t)NW * NB * CPW * 8;    // 8 MB
  int* sel_idx = (int*)(ws + off);                   off += (size_t)NB * TOPK * 4;
  float* sel_w = (float*)(ws + off);                 off += (size_t)NB * TOPK * 4;

  hipLaunchKernelGGL(qproj_kernel, dim3(NB), dim3(256), 0, stream, query, Wq, bq, qs);
  hipLaunchKernelGGL(score_topk_kernel, dim3(NW), dim3(64), 0, stream,
                     keys, qs, sums, cands);
  hipLaunchKernelGGL(merge_kernel, dim3(NB), dim3(256), 0, stream,
                     sums, cands, sel_idx, sel_w);
  hipLaunchKernelGGL(gather_kernel, dim3(NB * TOPK), dim3(64), 0, stream,
                     values, sel_idx, sel_w, out);
}